// Round 12
// baseline (251.564 us; speedup 1.0000x reference)
//
#include <hip/hip_runtime.h>
#include <hip/hip_bf16.h>

#define ACTIONS 64
#define EMB 32
#define DELTA 16
#define EPS 1e-5f

typedef float f32x4 __attribute__((ext_vector_type(4)));

// tanh(x) = 1 - 2/(1+exp(2x)); saturates correctly at +-1.
__device__ __forceinline__ float fast_tanhf(float x) {
    float e = __expf(2.0f * x);
    float r = __builtin_amdgcn_rcpf(1.0f + e);
    return 1.0f - 2.0f * r;
}

// ====================  DIAGNOSTIC PROBES (this round only)  ================
// Both write 537 MB to d_out (4 full passes) so they rank in the top-5
// rocprof rows next to the 537-MB harness fills -> their hbm_gbps is directly
// readable. Real kernels run afterwards and overwrite everything.

// Probe A: exact replica of spline_main's store pattern. 1024 blocks x 256,
// same LDS footprint (38.9 KB -> 4 blocks/CU), nt stores, 1 KiB wave
// segments at 8 KiB stride. 4 passes with rotated rowtile (distinct addrs
// per thread per pass -> no dead-store elimination).
__global__ void __launch_bounds__(256) probe_pattern_kernel(f32x4* __restrict__ out4,
                                                            int opaque_zero) {
    __shared__ char dummy[38912];
    const int tid = threadIdx.x;
    dummy[tid] = (char)opaque_zero;
    __syncthreads();

    const int colgrp  = blockIdx.x & 7;
    const int rowtile = blockIdx.x >> 3;
    const int c0      = colgrp * 8;
    const int ci      = (tid >> 3) & 7;
    const int e4      = tid & 7;
    const int row_off = tid >> 6;

    f32x4 v = {1.f, 2.f, 3.f, 4.f};
    if (dummy[(tid * 7) & 255] == 137) v.x += 1.0f;   // opaque LDS keep-alive

    #pragma unroll
    for (int p = 0; p < 4; ++p) {
        const int rt = (rowtile + p * 32) & 127;
        const int r0 = rt * 128;
        #pragma unroll 4
        for (int it = 0; it < 32; ++it) {
            const int rl = it * 4 + row_off;
            __builtin_nontemporal_store(v, &out4[((r0 + rl) * ACTIONS + c0 + ci) * 8 + e4]);
        }
    }
}

// Probe B: fill-style fully-linear nt stores. 2048 blocks x 256, no LDS.
__global__ void __launch_bounds__(256) probe_linear_kernel(f32x4* __restrict__ out4) {
    const int gtid = blockIdx.x * 256 + threadIdx.x;   // 0..524287
    f32x4 v = {1.f, 2.f, 3.f, 4.f};
    #pragma unroll
    for (int p = 0; p < 4; ++p) {
        const int base = (gtid + p * 131072) & 524287;
        #pragma unroll 4
        for (int i = 0; i < 16; ++i) {
            __builtin_nontemporal_store(v, &out4[base + i * 524288]);
        }
    }
}

// ---------------- Kernel 1: per-column partial sums (exact R6 = 35.5us) ----
__global__ void __launch_bounds__(256) bn_stats_kernel(const f32x4* __restrict__ x4,
                                                       float* __restrict__ partial,
                                                       int total4 /* n*64/4 */) {
    const int tid = threadIdx.x;
    f32x4 s = {0.f, 0.f, 0.f, 0.f};
    f32x4 q = {0.f, 0.f, 0.f, 0.f};
    const int stride = gridDim.x * 256;
    for (int i = blockIdx.x * 256 + tid; i < total4; i += stride) {
        f32x4 v = x4[i];
        s += v;
        q += v * v;
    }
    __shared__ f32x4 ssum[256];
    __shared__ f32x4 ssq[256];
    ssum[tid] = s;
    ssq[tid] = q;
    __syncthreads();
    if (tid < 16) {
        f32x4 a = ssum[tid];
        f32x4 b = ssq[tid];
        #pragma unroll
        for (int k = 1; k < 16; ++k) {
            a += ssum[tid + 16 * k];
            b += ssq[tid + 16 * k];
        }
        float* ps = partial + blockIdx.x * 128;
        #pragma unroll
        for (int j = 0; j < 4; ++j) {
            ps[4 * tid + j]      = a[j];
            ps[64 + 4 * tid + j] = b[j];
        }
    }
}

// ---------------- Kernel 2: main spline-embedding (exact R6 = 35.5us) ------
__global__ void __launch_bounds__(256) spline_main_kernel(
        const f32x4* __restrict__ x4,
        const f32x4* __restrict__ emb4,
        const float* __restrict__ partial,
        const float* __restrict__ bn_w,
        const float* __restrict__ bn_b,
        f32x4* __restrict__ out4,
        float inv_n, int nstat) {
    __shared__ f32x4 tab4[33 * 64];     // 33 KB  [knot][ci][e4]
    __shared__ f32x4 xs4[256];          //  4 KB  128 rows x 8 cols
    __shared__ float psum[2][8][8];     // [half][ci][chunk]

    const int tid     = threadIdx.x;
    const int colgrp  = blockIdx.x & 7;
    const int rowtile = blockIdx.x >> 3;
    const int c0      = colgrp * 8;
    const int r0      = rowtile * 128;

    // stage x slice first (oldest vmcnt entries retire first), then table
    xs4[tid] = x4[(r0 + (tid >> 1)) * 16 + (c0 >> 2) + (tid & 1)];
    for (int u = tid; u < 33 * 64; u += 256) {
        tab4[u] = emb4[(u >> 6) * 512 + c0 * 8 + (u & 63)];
    }
    // fold stats partials for these 8 cols (fixed order -> deterministic)
    if (tid < 128) {
        const int pci = tid & 7, half = (tid >> 3) & 1, chunk = tid >> 4;
        float s = 0.f;
        for (int k = 0; k < 16; ++k)
            s += partial[(chunk * 16 + k) * 128 + half * 64 + c0 + pci];
        psum[half][pci][chunk] = s;
    }
    __syncthreads();

    const int ci      = (tid >> 3) & 7;   // column within group
    const int e4      = tid & 7;          // float4 within emb row
    const int row_off = tid >> 6;         // wave id 0..3
    float scale, shift;
    {
        float S = 0.f, Q = 0.f;
        #pragma unroll
        for (int k = 0; k < 8; ++k) { S += psum[0][ci][k]; Q += psum[1][ci][k]; }
        const float mean = S * inv_n;
        const float var  = fmaxf(Q * inv_n - mean * mean, 0.0f);
        scale = rsqrtf(var + EPS) * bn_w[c0 + ci];
        shift = bn_b[c0 + ci] - mean * scale;
    }

    // ---- steady store loop: zero global loads, nt stores ----
    const float* xs = (const float*)xs4;
    #pragma unroll 4
    for (int it = 0; it < 32; ++it) {
        const int rl = it * 4 + row_off;             // local row
        const float xv = xs[rl * 8 + ci];            // LDS broadcast read

        float t = fast_tanhf(fmaf(xv, scale, shift));
        t = fminf(fmaxf(t, -1.0f + 1e-5f), 1.0f - 1e-5f);

        const float td  = t * (float)DELTA;
        const float xlf = floorf(td);
        const float xhf = floorf(td + 1.0f);         // mirror reference
        const int kl = (int)xlf + DELTA;             // 0..31
        const int kh = (int)xhf + DELTA;             // 1..32
        const float wl = xhf - td;
        const float wh = td - xlf;

        const f32x4 bl = tab4[kl * 64 + ci * 8 + e4];
        const f32x4 bh = tab4[kh * 64 + ci * 8 + e4];
        f32x4 o = bh * wh + bl * wl;
        __builtin_nontemporal_store(o, &out4[((r0 + rl) * ACTIONS + c0 + ci) * 8 + e4]);
    }
    (void)nstat;
}

extern "C" void kernel_launch(void* const* d_in, const int* in_sizes, int n_in,
                              void* d_out, int out_size, void* d_ws, size_t ws_size,
                              hipStream_t stream) {
    const float* x    = (const float*)d_in[0];
    const float* bn_w = (const float*)d_in[1];
    const float* bn_b = (const float*)d_in[2];
    const float* emb  = (const float*)d_in[3];
    float* out        = (float*)d_out;

    const int n = in_sizes[0] / ACTIONS;   // 16384
    const int total = n * ACTIONS;

    float* partial = (float*)d_ws;         // 128 * 128 floats

    // ---- diagnostic probes (overwritten by the real kernels below) ----
    probe_pattern_kernel<<<1024, 256, 0, stream>>>((f32x4*)out, 0);
    probe_linear_kernel<<<2048, 256, 0, stream>>>((f32x4*)out);

    // ---- real computation (exact R6 35.5us configuration) ----
    const int STATS_BLOCKS = 128;
    bn_stats_kernel<<<STATS_BLOCKS, 256, 0, stream>>>((const f32x4*)x, partial, total / 4);

    const int blocks = 8 * (n / 128);      // 1024 (4/CU, 38.9 KB LDS)
    spline_main_kernel<<<blocks, 256, 0, stream>>>((const f32x4*)x, (const f32x4*)emb,
                                                   partial, bn_w, bn_b, (f32x4*)out,
                                                   1.0f / (float)n, STATS_BLOCKS);
}

// Round 13
// 38.233 us; speedup vs baseline: 6.5798x; 6.5798x over previous
//
#include <hip/hip_runtime.h>
#include <hip/hip_bf16.h>

#define ACTIONS 64
#define EMB 32
#define DELTA 16
#define EPS 1e-5f

typedef float f32x4 __attribute__((ext_vector_type(4)));

// tanh(x) = 1 - 2/(1+exp(2x)); saturates correctly at +-1.
__device__ __forceinline__ float fast_tanhf(float x) {
    float e = __expf(2.0f * x);
    float r = __builtin_amdgcn_rcpf(1.0f + e);
    return 1.0f - 2.0f * r;
}

// ---------------- Kernel 1: per-column partial sums (R6-proven) ------------
__global__ void __launch_bounds__(256) bn_stats_kernel(const f32x4* __restrict__ x4,
                                                       float* __restrict__ partial,
                                                       int total4 /* n*64/4 */) {
    const int tid = threadIdx.x;
    f32x4 s = {0.f, 0.f, 0.f, 0.f};
    f32x4 q = {0.f, 0.f, 0.f, 0.f};
    const int stride = gridDim.x * 256;
    for (int i = blockIdx.x * 256 + tid; i < total4; i += stride) {
        f32x4 v = x4[i];
        s += v;
        q += v * v;
    }
    __shared__ f32x4 ssum[256];
    __shared__ f32x4 ssq[256];
    ssum[tid] = s;
    ssq[tid] = q;
    __syncthreads();
    if (tid < 16) {
        f32x4 a = ssum[tid];
        f32x4 b = ssq[tid];
        #pragma unroll
        for (int k = 1; k < 16; ++k) {
            a += ssum[tid + 16 * k];
            b += ssq[tid + 16 * k];
        }
        float* ps = partial + blockIdx.x * 128;
        #pragma unroll
        for (int j = 0; j < 4; ++j) {
            ps[4 * tid + j]      = a[j];
            ps[64 + 4 * tid + j] = b[j];
        }
    }
}

// ---------------- Kernel 2: main spline-embedding -------------------------
// R6 structure (8 cols x 128 rows/block, 4 blocks/CU, zero global loads in
// steady loop, nt stores). R12 probes proved this exact store pattern does
// 6.9 TB/s when stores are dependency-free. THIS ROUND (single variable):
// fully register-staged chunks — phase A computes 8 output f32x4 into
// registers (all LDS reads + tanh + fma), phase B issues 8 PURE nt stores
// with no lgkm waits. Chunk order staggered per wave (wave w starts at chunk
// w&3) so A/B phases de-phase across a SIMD's 4 waves -> continuous stores.
__global__ void __launch_bounds__(256) spline_main_kernel(
        const f32x4* __restrict__ x4,
        const f32x4* __restrict__ emb4,
        const float* __restrict__ partial,
        const float* __restrict__ bn_w,
        const float* __restrict__ bn_b,
        f32x4* __restrict__ out4,
        float inv_n) {
    __shared__ f32x4 tab4[33 * 64];     // 33 KB  [knot][ci][e4]
    __shared__ f32x4 xs4[256];          //  4 KB  128 rows x 8 cols
    __shared__ float psum[2][8][8];     // [half][ci][chunk]

    const int tid     = threadIdx.x;
    const int colgrp  = blockIdx.x & 7;
    const int rowtile = blockIdx.x >> 3;
    const int c0      = colgrp * 8;
    const int r0      = rowtile * 128;

    // stage x slice first (oldest vmcnt entries retire first), then table
    xs4[tid] = x4[(r0 + (tid >> 1)) * 16 + (c0 >> 2) + (tid & 1)];
    for (int u = tid; u < 33 * 64; u += 256) {
        tab4[u] = emb4[(u >> 6) * 512 + c0 * 8 + (u & 63)];
    }
    // fold stats partials for these 8 cols (fixed order -> deterministic)
    if (tid < 128) {
        const int pci = tid & 7, half = (tid >> 3) & 1, chunk = tid >> 4;
        float s = 0.f;
        for (int k = 0; k < 16; ++k)
            s += partial[(chunk * 16 + k) * 128 + half * 64 + c0 + pci];
        psum[half][pci][chunk] = s;
    }
    __syncthreads();

    const int ci      = (tid >> 3) & 7;   // column within group
    const int e4      = tid & 7;          // float4 within emb row
    const int row_off = tid >> 6;         // wave id 0..3
    float scale, shift;
    {
        float S = 0.f, Q = 0.f;
        #pragma unroll
        for (int k = 0; k < 8; ++k) { S += psum[0][ci][k]; Q += psum[1][ci][k]; }
        const float mean = S * inv_n;
        const float var  = fmaxf(Q * inv_n - mean * mean, 0.0f);
        scale = rsqrtf(var + EPS) * bn_w[c0 + ci];
        shift = bn_b[c0 + ci] - mean * scale;
    }

    // ---- steady loop: 4 chunks x 8 rows; reg-staged, wave-staggered ----
    const float* xs = (const float*)xs4;
    const char* tabB = (const char*)tab4;
    const int lane_off = (ci * 8 + e4) * 16;    // byte offset within knot row

    for (int cc = 0; cc < 4; ++cc) {
        const int c = (cc + row_off) & 3;        // per-wave stagger
        // phase A: compute 8 outputs fully into registers
        f32x4 o[8];
        #pragma unroll
        for (int j = 0; j < 8; ++j) {
            const int rl = c * 32 + j * 4 + row_off;     // local row
            const float xv = xs[rl * 8 + ci];            // LDS broadcast read
            float t = fast_tanhf(fmaf(xv, scale, shift));
            t = fminf(fmaxf(t, -1.0f + 1e-5f), 1.0f - 1e-5f);
            const float td  = t * (float)DELTA;
            const float xlf = floorf(td);
            const float xhf = floorf(td + 1.0f);         // mirror reference
            const int kl = (int)xlf + DELTA;             // 0..31 (kh = kl+1)
            const int off = kl * 1024 + lane_off;        // 1 KiB per knot row
            const float wl = xhf - td;
            const float wh = td - xlf;
            const f32x4 bl = *reinterpret_cast<const f32x4*>(tabB + off);
            const f32x4 bh = *reinterpret_cast<const f32x4*>(tabB + off + 1024);
            o[j] = bh * wh + bl * wl;
        }
        // phase B: 8 pure nt stores, no waits in between
        #pragma unroll
        for (int j = 0; j < 8; ++j) {
            const int rl = c * 32 + j * 4 + row_off;
            __builtin_nontemporal_store(o[j], &out4[((r0 + rl) * ACTIONS + c0 + ci) * 8 + e4]);
        }
    }
}

extern "C" void kernel_launch(void* const* d_in, const int* in_sizes, int n_in,
                              void* d_out, int out_size, void* d_ws, size_t ws_size,
                              hipStream_t stream) {
    const float* x    = (const float*)d_in[0];
    const float* bn_w = (const float*)d_in[1];
    const float* bn_b = (const float*)d_in[2];
    const float* emb  = (const float*)d_in[3];
    float* out        = (float*)d_out;

    const int n = in_sizes[0] / ACTIONS;   // 16384
    const int total = n * ACTIONS;

    float* partial = (float*)d_ws;         // 128 * 128 floats

    const int STATS_BLOCKS = 128;
    bn_stats_kernel<<<STATS_BLOCKS, 256, 0, stream>>>((const f32x4*)x, partial, total / 4);

    const int blocks = 8 * (n / 128);      // 1024 (4/CU, 38.9 KB LDS)
    spline_main_kernel<<<blocks, 256, 0, stream>>>((const f32x4*)x, (const f32x4*)emb,
                                                   partial, bn_w, bn_b, (f32x4*)out,
                                                   1.0f / (float)n);
}